// Round 2
// baseline (354.039 us; speedup 1.0000x reference)
//
#include <hip/hip_runtime.h>
#include <math.h>

// ---- problem dims (B=2, T=2048, C=1024, H=16, HS=64) ----
#define BB 2
#define TT 2048
#define CC 1024
#define HH 16
#define HS 64
#define MT 4096   // B*T
#define FF 4096   // 4*C

typedef unsigned short u16;
typedef __bf16 bfrag __attribute__((ext_vector_type(8)));
typedef float f4 __attribute__((ext_vector_type(4)));

#define AS1(p) ((const __attribute__((address_space(1))) void*)(p))
#define AS3(p) ((__attribute__((address_space(3))) void*)(p))

__device__ __forceinline__ u16 f2bf(float f) {
  union { float f; unsigned u; } a; a.f = f;
  return (u16)((a.u + 0x7fffu + ((a.u >> 16) & 1u)) >> 16);
}

// XOR-swizzle for 128-byte-row LDS tiles: spreads 8 consecutive rows across
// 8 distinct 16B slots -> wave64 ds_read_b128 lands at 2-way aliasing (free).
__device__ __forceinline__ int swz128(int byteoff) {
  return byteoff ^ (((byteoff >> 7) & 7) << 4);
}

// ------------------------------------------------------------------
// Tiled transpose f32 -> bf16.
// ------------------------------------------------------------------
__global__ void tr_f32_bf16(const float* __restrict__ src, u16* __restrict__ dst,
                            int R, int Cc, long long sb, long long db, int dld) {
  __shared__ float t[32][33];
  const int bz = blockIdx.z;
  const int r0 = blockIdx.y * 32, c0 = blockIdx.x * 32;
  const int tx = threadIdx.x, ty = threadIdx.y;
  const float* s = src + bz * sb;
  u16* d = dst + bz * db;
#pragma unroll
  for (int i = 0; i < 4; i++)
    t[ty + i * 8][tx] = s[(size_t)(r0 + ty + i * 8) * Cc + c0 + tx];
  __syncthreads();
#pragma unroll
  for (int i = 0; i < 4; i++)
    d[(size_t)(c0 + ty + i * 8) * dld + r0 + tx] = f2bf(t[tx][ty + i * 8]);
}

// bf16 -> bf16 transpose (for V)
__global__ void tr_bf16(const u16* __restrict__ src, u16* __restrict__ dst,
                        int R, int Cc, long long sb, long long db, int dld) {
  __shared__ u16 t[32][33];
  const int bz = blockIdx.z;
  const int r0 = blockIdx.y * 32, c0 = blockIdx.x * 32;
  const int tx = threadIdx.x, ty = threadIdx.y;
  const u16* s = src + bz * sb;
  u16* d = dst + bz * db;
#pragma unroll
  for (int i = 0; i < 4; i++)
    t[ty + i * 8][tx] = s[(size_t)(r0 + ty + i * 8) * Cc + c0 + tx];
  __syncthreads();
#pragma unroll
  for (int i = 0; i < 4; i++)
    d[(size_t)(c0 + ty + i * 8) * dld + r0 + tx] = t[tx][ty + i * 8];
}

// ------------------------------------------------------------------
// LayerNorm: one block (256 thr) per row of [4096][1024] f32 -> bf16
// ------------------------------------------------------------------
__global__ __launch_bounds__(256) void ln_kernel(
    const float* __restrict__ x, const float* __restrict__ w,
    const float* __restrict__ b, u16* __restrict__ y) {
  const int row = blockIdx.x, tid = threadIdx.x;
  const float4 v = reinterpret_cast<const float4*>(x + (size_t)row * CC)[tid];
  float s = v.x + v.y + v.z + v.w;
  float s2 = v.x * v.x + v.y * v.y + v.z * v.z + v.w * v.w;
#pragma unroll
  for (int off = 32; off >= 1; off >>= 1) {
    s += __shfl_xor(s, off);
    s2 += __shfl_xor(s2, off);
  }
  __shared__ float ps[4], ps2[4];
  const int wave = tid >> 6, lane = tid & 63;
  if (lane == 0) { ps[wave] = s; ps2[wave] = s2; }
  __syncthreads();
  s = ps[0] + ps[1] + ps[2] + ps[3];
  s2 = ps2[0] + ps2[1] + ps2[2] + ps2[3];
  const float mu = s * (1.f / CC);
  const float rstd = rsqrtf(s2 * (1.f / CC) - mu * mu + 1e-5f);
  const float4 wv = reinterpret_cast<const float4*>(w)[tid];
  const float4 bv = reinterpret_cast<const float4*>(b)[tid];
  ushort4 o;
  o.x = f2bf((v.x - mu) * rstd * wv.x + bv.x);
  o.y = f2bf((v.y - mu) * rstd * wv.y + bv.y);
  o.z = f2bf((v.z - mu) * rstd * wv.z + bv.z);
  o.w = f2bf((v.w - mu) * rstd * wv.w + bv.w);
  reinterpret_cast<ushort4*>(y + (size_t)row * CC)[tid] = o;
}

// ------------------------------------------------------------------
// 128x128 bf16 MFMA GEMM core (m97-style).  A [M][K], Bt [N][K] row-major.
// ------------------------------------------------------------------
__device__ __forceinline__ void gemm128_core(
    const u16* __restrict__ A, const u16* __restrict__ Bt, int K,
    f4 (&acc)[4][4]) {
  __shared__ u16 As[128 * 32];
  __shared__ u16 Bs[128 * 32];
  const int tid = threadIdx.x;
  const int wave = tid >> 6, lane = tid & 63;
  const int wm = wave >> 1, wn = wave & 1;
  const int lg = lane >> 4, ll = lane & 15;

  const u16* ga = A + (size_t)(blockIdx.y * 128 + (tid >> 2)) * K + (tid & 3) * 8;
  const u16* gb = Bt + (size_t)(blockIdx.x * 128 + (tid >> 2)) * K + (tid & 3) * 8;
  u16* la = As + tid * 8;
  u16* lb = Bs + tid * 8;
  const size_t g64 = (size_t)64 * K;

  for (int kt = 0; kt < K; kt += 32) {
    __builtin_amdgcn_global_load_lds(AS1(ga), AS3(la), 16, 0, 0);
    __builtin_amdgcn_global_load_lds(AS1(ga + g64), AS3(la + 2048), 16, 0, 0);
    __builtin_amdgcn_global_load_lds(AS1(gb), AS3(lb), 16, 0, 0);
    __builtin_amdgcn_global_load_lds(AS1(gb + g64), AS3(lb + 2048), 16, 0, 0);
    __syncthreads();
    bfrag af[4], bf[4];
#pragma unroll
    for (int i = 0; i < 4; i++) {
      af[i] = *(const bfrag*)&As[(wm * 64 + i * 16 + ll) * 32 + lg * 8];
      bf[i] = *(const bfrag*)&Bs[(wn * 64 + i * 16 + ll) * 32 + lg * 8];
    }
#pragma unroll
    for (int i = 0; i < 4; i++)
#pragma unroll
      for (int j = 0; j < 4; j++)
        acc[i][j] = __builtin_amdgcn_mfma_f32_16x16x32_bf16(af[i], bf[j], acc[i][j], 0, 0, 0);
    __syncthreads();
    ga += 32; gb += 32;
  }
}

// C/D frag mapping (verified m89): col = lane&15, row = (lane>>4)*4 + r
#define EPI_COORDS                                              \
  const int tid = threadIdx.x;                                  \
  const int wave = tid >> 6, lane = tid & 63;                   \
  const int wm = wave >> 1, wn = wave & 1;                      \
  const int lg = lane >> 4, ll = lane & 15;

// QKV: N=3072 (q|k|v), bias add, fold 1/32 into q, scatter to [BH][T][HS]
__global__ __launch_bounds__(256, 2) void gemm_qkv(
    const u16* __restrict__ A, const u16* __restrict__ Bt,
    const float* __restrict__ bq, const float* __restrict__ bk,
    const float* __restrict__ bv,
    u16* __restrict__ q, u16* __restrict__ k, u16* __restrict__ v) {
  f4 acc[4][4] = {};
  gemm128_core(A, Bt, CC, acc);
  EPI_COORDS
#pragma unroll
  for (int j = 0; j < 4; j++) {
    const int n = blockIdx.x * 128 + wn * 64 + j * 16 + ll;
    const int sec = n >> 10, nn = n & 1023, h = nn >> 6, d = nn & 63;
    const float bias = (sec == 0 ? bq : (sec == 1 ? bk : bv))[nn];
    const float scale = (sec == 0) ? 0.03125f : 1.0f;  // C^-0.5 folded into Q
    u16* dst = sec == 0 ? q : (sec == 1 ? k : v);
#pragma unroll
    for (int i = 0; i < 4; i++)
#pragma unroll
      for (int r = 0; r < 4; r++) {
        const int m = blockIdx.y * 128 + wm * 64 + i * 16 + lg * 4 + r;
        const int b = m >> 11, t = m & 2047;
        dst[(((size_t)b * HH + h) * TT + t) * HS + d] = f2bf((acc[i][j][r] + bias) * scale);
      }
  }
}

// PROJ: out = x + (A @ Wp + bp) -> f32 out buffer (= d_out)
__global__ __launch_bounds__(256, 2) void gemm_proj(
    const u16* __restrict__ A, const u16* __restrict__ Bt,
    const float* __restrict__ bp, const float* __restrict__ x,
    float* __restrict__ outw) {
  f4 acc[4][4] = {};
  gemm128_core(A, Bt, CC, acc);
  EPI_COORDS
#pragma unroll
  for (int i = 0; i < 4; i++)
#pragma unroll
    for (int j = 0; j < 4; j++) {
      const int n = blockIdx.x * 128 + wn * 64 + j * 16 + ll;
      const float bias = bp[n];
#pragma unroll
      for (int r = 0; r < 4; r++) {
        const int m = blockIdx.y * 128 + wm * 64 + i * 16 + lg * 4 + r;
        const size_t idx = (size_t)m * CC + n;
        outw[idx] = acc[i][j][r] + bias + x[idx];
      }
    }
}

// FFN1: h = gelu_exact(A @ W1 + b1) -> bf16 [4096][4096]
__global__ __launch_bounds__(256, 2) void gemm_ffn1(
    const u16* __restrict__ A, const u16* __restrict__ Bt,
    const float* __restrict__ b1, u16* __restrict__ hb) {
  f4 acc[4][4] = {};
  gemm128_core(A, Bt, CC, acc);
  EPI_COORDS
#pragma unroll
  for (int i = 0; i < 4; i++)
#pragma unroll
    for (int j = 0; j < 4; j++) {
      const int n = blockIdx.x * 128 + wn * 64 + j * 16 + ll;
      const float bias = b1[n];
#pragma unroll
      for (int r = 0; r < 4; r++) {
        const int m = blockIdx.y * 128 + wm * 64 + i * 16 + lg * 4 + r;
        const float t = acc[i][j][r] + bias;
        const float g = 0.5f * t * (1.0f + erff(t * 0.70710678118654752f));
        hb[(size_t)m * FF + n] = f2bf(g);
      }
    }
}

// FFN2: d_out = outw + (A @ W2 + b2)   (outw aliases d_out; same-index RMW)
__global__ __launch_bounds__(256, 2) void gemm_ffn2(
    const u16* __restrict__ A, const u16* __restrict__ Bt,
    const float* __restrict__ b2, const float* __restrict__ outw,
    float* __restrict__ dout) {
  f4 acc[4][4] = {};
  gemm128_core(A, Bt, FF, acc);
  EPI_COORDS
#pragma unroll
  for (int i = 0; i < 4; i++)
#pragma unroll
    for (int j = 0; j < 4; j++) {
      const int n = blockIdx.x * 128 + wn * 64 + j * 16 + ll;
      const float bias = b2[n];
#pragma unroll
      for (int r = 0; r < 4; r++) {
        const int m = blockIdx.y * 128 + wm * 64 + i * 16 + lg * 4 + r;
        const size_t idx = (size_t)m * CC + n;
        dout[idx] = acc[i][j][r] + bias + outw[idx];
      }
    }
}

// ------------------------------------------------------------------
// Flash attention fwd, v2: KVBLK=64, XOR-swizzled K/V/P LDS (2-way max),
// 2-phase double-buffered K/V staging with counted vmcnt (loads stay in
// flight across raw s_barrier).  Q,K: [32][2048][64] bf16 (Q pre-scaled),
// Vt: [32][64][2048] bf16.  grid (16 q-tiles, 32 bh), 256 thr (4 waves),
// each wave owns 32 q-rows.  LDS: 2*8 + 2*8 + 16 = 48 KB.
// ------------------------------------------------------------------
__global__ __launch_bounds__(256, 2) void attn_kernel(
    const u16* __restrict__ Q, const u16* __restrict__ Kb,
    const u16* __restrict__ Vt, u16* __restrict__ Ao) {
  __shared__ __align__(1024) u16 Ks[2][64 * 64];  // [s:64][d:64], swizzled
  __shared__ __align__(1024) u16 Vs[2][64 * 64];  // [d:64][s:64], swizzled
  __shared__ __align__(1024) u16 Ps[128 * 64];    // [qrow:128][s:64], swizzled
  const int bh = blockIdx.y, qt = blockIdx.x;
  const int tid = threadIdx.x, wave = tid >> 6, lane = tid & 63;
  const int lg = lane >> 4, ll = lane & 15;

  // Q fragments in registers (A-operand layout: row = ll, k contiguous)
  bfrag qf[2][2];
  const u16* Qb = Q + ((size_t)bh * TT + qt * 128 + wave * 32) * HS;
#pragma unroll
  for (int m2 = 0; m2 < 2; m2++)
#pragma unroll
    for (int ks = 0; ks < 2; ks++)
      qf[m2][ks] = *(const bfrag*)&Qb[(m2 * 16 + ll) * HS + ks * 32 + lg * 8];

  f4 o[2][4] = {};
  float mrow[2][4], lrow[2][4];
#pragma unroll
  for (int m2 = 0; m2 < 2; m2++)
#pragma unroll
    for (int r = 0; r < 4; r++) { mrow[m2][r] = -INFINITY; lrow[m2][r] = 0.f; }

  // staging: dest is LINEAR (global_load_lds writes base+lane*16); the
  // SOURCE chunk index is pre-swizzled so that swizzled reads see row-major.
  const int trow = tid >> 3;                 // dest row within 32-row half
  const int tch  = (tid & 7) ^ (trow & 7);   // pre-swizzled source chunk
  const u16* gk = Kb + ((size_t)bh * TT + trow) * HS + tch * 8;
  const u16* gv = Vt + ((size_t)bh * HS + trow) * TT + tch * 8;

  char* const pbase = (char*)Ps;

#define STAGE(bufi, stt)                                                          \
  do {                                                                            \
    u16* lk = &Ks[bufi][tid * 8];                                                 \
    u16* lv = &Vs[bufi][tid * 8];                                                 \
    __builtin_amdgcn_global_load_lds(AS1(gk + (size_t)(stt) * HS), AS3(lk), 16, 0, 0); \
    __builtin_amdgcn_global_load_lds(AS1(gk + (size_t)(stt) * HS + 32 * HS), AS3(lk + 2048), 16, 0, 0); \
    __builtin_amdgcn_global_load_lds(AS1(gv + (stt)), AS3(lv), 16, 0, 0);         \
    __builtin_amdgcn_global_load_lds(AS1(gv + (stt) + (size_t)32 * TT), AS3(lv + 2048), 16, 0, 0); \
  } while (0)

  STAGE(0, 0);
  int cur = 0;

  for (int st = 0; st < TT; st += 64) {
    if (st + 64 < TT) {
      STAGE(cur ^ 1, st + 64);
      asm volatile("s_waitcnt vmcnt(4)" ::: "memory");  // current buffer ready, next stays in flight
    } else {
      asm volatile("s_waitcnt vmcnt(0)" ::: "memory");
    }
    __builtin_amdgcn_s_barrier();
    __builtin_amdgcn_sched_barrier(0);

    const char* kbuf = (const char*)Ks[cur];
    const char* vbuf = (const char*)Vs[cur];

    // S = Q K^T  (32 q-rows x 64 s per wave)
    f4 s[2][4];
#pragma unroll
    for (int j = 0; j < 4; j++) {
      const int row = j * 16 + ll;
      const bfrag k0 = *(const bfrag*)(kbuf + swz128(row * 128 + lg * 16));
      const bfrag k1 = *(const bfrag*)(kbuf + swz128(row * 128 + 64 + lg * 16));
#pragma unroll
      for (int m2 = 0; m2 < 2; m2++) {
        f4 z = {0.f, 0.f, 0.f, 0.f};
        z = __builtin_amdgcn_mfma_f32_16x16x32_bf16(qf[m2][0], k0, z, 0, 0, 0);
        s[m2][j] = __builtin_amdgcn_mfma_f32_16x16x32_bf16(qf[m2][1], k1, z, 0, 0, 0);
      }
    }

    // online softmax (rows live in 16-lane groups; 4 rows/lane as regs)
#pragma unroll
    for (int m2 = 0; m2 < 2; m2++) {
      float al[4], rs[4];
#pragma unroll
      for (int r = 0; r < 4; r++) {
        float t0 = s[m2][0][r];
#pragma unroll
        for (int j = 1; j < 4; j++) t0 = fmaxf(t0, s[m2][j][r]);
#pragma unroll
        for (int off = 1; off < 16; off <<= 1) t0 = fmaxf(t0, __shfl_xor(t0, off, 16));
        const float mn = fmaxf(mrow[m2][r], t0);
        al[r] = __expf(mrow[m2][r] - mn);
        mrow[m2][r] = mn;
        rs[r] = 0.f;
      }
#pragma unroll
      for (int j = 0; j < 4; j++)
#pragma unroll
        for (int r = 0; r < 4; r++) {
          const float p = __expf(s[m2][j][r] - mrow[m2][r]);
          s[m2][j][r] = p;
          rs[r] += p;
        }
#pragma unroll
      for (int r = 0; r < 4; r++) {
#pragma unroll
        for (int off = 1; off < 16; off <<= 1) rs[r] += __shfl_xor(rs[r], off, 16);
        lrow[m2][r] = lrow[m2][r] * al[r] + rs[r];
      }
#pragma unroll
      for (int fo = 0; fo < 4; fo++)
#pragma unroll
        for (int r = 0; r < 4; r++) o[m2][fo][r] *= al[r];
      // P -> LDS (C/D layout -> row-major, swizzled). Wave-private rows:
      // no barrier needed; within-wave lgkmcnt orders write->read.
#pragma unroll
      for (int j = 0; j < 4; j++)
#pragma unroll
        for (int r = 0; r < 4; r++) {
          const int prow = wave * 32 + m2 * 16 + lg * 4 + r;
          *(u16*)(pbase + swz128(prow * 128 + (j * 16 + ll) * 2)) = f2bf(s[m2][j][r]);
        }
    }

    // O += P V
#pragma unroll
    for (int ks = 0; ks < 2; ks++) {
      bfrag pf[2];
#pragma unroll
      for (int m2 = 0; m2 < 2; m2++)
        pf[m2] = *(const bfrag*)(pbase + swz128((wave * 32 + m2 * 16 + ll) * 128 + ks * 64 + lg * 16));
#pragma unroll
      for (int fo = 0; fo < 4; fo++) {
        const bfrag vf = *(const bfrag*)(vbuf + swz128((fo * 16 + ll) * 128 + ks * 64 + lg * 16));
#pragma unroll
        for (int m2 = 0; m2 < 2; m2++)
          o[m2][fo] = __builtin_amdgcn_mfma_f32_16x16x32_bf16(pf[m2], vf, o[m2][fo], 0, 0, 0);
      }
    }

    __builtin_amdgcn_sched_barrier(0);
    __builtin_amdgcn_s_barrier();  // all waves done reading buf[cur] before restage
    cur ^= 1;
  }
#undef STAGE

  // epilogue: O / l, concat heads -> [B*T][C] bf16
  const int b = bh >> 4, h = bh & 15;
#pragma unroll
  for (int m2 = 0; m2 < 2; m2++)
#pragma unroll
    for (int r = 0; r < 4; r++) {
      const float inv = 1.0f / lrow[m2][r];
      const int t = qt * 128 + wave * 32 + m2 * 16 + lg * 4 + r;
#pragma unroll
      for (int fo = 0; fo < 4; fo++)
        Ao[((size_t)b * TT + t) * CC + h * HS + fo * 16 + ll] = f2bf(o[m2][fo][r] * inv);
    }
}

// ------------------------------------------------------------------
extern "C" void kernel_launch(void* const* d_in, const int* in_sizes, int n_in,
                              void* d_out, int out_size, void* d_ws, size_t ws_size,
                              hipStream_t stream) {
  const float* x    = (const float*)d_in[0];
  const float* Wq   = (const float*)d_in[1];
  const float* bq   = (const float*)d_in[2];
  const float* Wk   = (const float*)d_in[3];
  const float* bk   = (const float*)d_in[4];
  const float* Wv   = (const float*)d_in[5];
  const float* bv   = (const float*)d_in[6];
  const float* Wp   = (const float*)d_in[7];
  const float* bp   = (const float*)d_in[8];
  const float* W1   = (const float*)d_in[9];
  const float* b1   = (const float*)d_in[10];
  const float* W2   = (const float*)d_in[11];
  const float* b2   = (const float*)d_in[12];
  const float* ln1w = (const float*)d_in[13];
  const float* ln1b = (const float*)d_in[14];
  const float* ln2w = (const float*)d_in[15];
  const float* ln2b = (const float*)d_in[16];
  float* dout = (float*)d_out;

  char* ws = (char*)d_ws;
  u16* wqkv = (u16*)(ws + 0);          // [3072][1024]  6.29 MB
  u16* wpt  = (u16*)(ws + 6291456);    // [1024][1024]  2.10 MB
  u16* w1t  = (u16*)(ws + 8388608);    // [4096][1024]  8.39 MB
  u16* w2t  = (u16*)(ws + 16777216);   // [1024][4096]  8.39 MB
  u16* xn   = (u16*)(ws + 25165824);   // [4096][1024]  8.39 MB (reused as LN2 out)
  u16* qb   = (u16*)(ws + 33554432);   // [32][2048][64]
  u16* kb   = (u16*)(ws + 41943040);
  u16* vb   = (u16*)(ws + 50331648);
  u16* vt   = (u16*)(ws + 58720256);   // [32][64][2048]
  u16* ao   = (u16*)(ws + 67108864);   // [4096][1024]
  u16* hb   = qb;                      // FFN hidden overlays q/k/v/vt (33.55 MB)

  dim3 blk256(256);
  dim3 blkT(32, 8);

  // weight prep: transpose to [N][K] bf16
  tr_f32_bf16<<<dim3(2, 32, 16), blkT, 0, stream>>>(Wq, wqkv,               1024,   64, 65536LL, 65536LL, 1024);
  tr_f32_bf16<<<dim3(2, 32, 16), blkT, 0, stream>>>(Wk, wqkv + 1024 * 1024, 1024,   64, 65536LL, 65536LL, 1024);
  tr_f32_bf16<<<dim3(2, 32, 16), blkT, 0, stream>>>(Wv, wqkv + 2048 * 1024, 1024,   64, 65536LL, 65536LL, 1024);
  tr_f32_bf16<<<dim3(32, 32, 1),  blkT, 0, stream>>>(Wp, wpt, 1024, 1024, 0LL, 0LL, 1024);
  tr_f32_bf16<<<dim3(128, 32, 1), blkT, 0, stream>>>(W1, w1t, 1024, 4096, 0LL, 0LL, 1024);
  tr_f32_bf16<<<dim3(32, 128, 1), blkT, 0, stream>>>(W2, w2t, 4096, 1024, 0LL, 0LL, 4096);

  // LN1 -> xn (bf16)
  ln_kernel<<<dim3(MT), blk256, 0, stream>>>(x, ln1w, ln1b, xn);

  // QKV projection (q pre-scaled by C^-0.5)
  gemm_qkv<<<dim3(24, 32), blk256, 0, stream>>>(xn, wqkv, bq, bk, bv, qb, kb, vb);

  // V -> Vt [bh][64][2048]
  tr_bf16<<<dim3(2, 64, 32), blkT, 0, stream>>>(vb, vt, 2048, 64, 131072LL, 131072LL, 2048);

  // attention
  attn_kernel<<<dim3(16, 32), blk256, 0, stream>>>(qb, kb, vt, ao);

  // out = x + ao @ Wp + bp   (f32, into d_out)
  gemm_proj<<<dim3(8, 32), blk256, 0, stream>>>(ao, wpt, bp, x, dout);

  // LN2 -> xn (reuse)
  ln_kernel<<<dim3(MT), blk256, 0, stream>>>(dout, ln2w, ln2b, xn);

  // FFN
  gemm_ffn1<<<dim3(32, 32), blk256, 0, stream>>>(xn, w1t, b1, hb);
  gemm_ffn2<<<dim3(8, 32), blk256, 0, stream>>>(hb, w2t, b2, dout, dout);
}

// Round 3
// 298.009 us; speedup vs baseline: 1.1880x; 1.1880x over previous
//
#include <hip/hip_runtime.h>
#include <math.h>

// ---- problem dims (B=2, T=2048, C=1024, H=16, HS=64) ----
#define BB 2
#define TT 2048
#define CC 1024
#define HH 16
#define HS 64
#define MT 4096   // B*T
#define FF 4096   // 4*C

typedef unsigned short u16;
typedef __bf16 bfrag __attribute__((ext_vector_type(8)));
typedef float f4 __attribute__((ext_vector_type(4)));

#define AS1(p) ((const __attribute__((address_space(1))) void*)(p))
#define AS3(p) ((__attribute__((address_space(3))) void*)(p))

__device__ __forceinline__ u16 f2bf(float f) {
  union { float f; unsigned u; } a; a.f = f;
  return (u16)((a.u + 0x7fffu + ((a.u >> 16) & 1u)) >> 16);
}

// XOR-swizzle for 128-byte-row LDS tiles: spreads 8 consecutive rows across
// 8 distinct 16B slots -> wave64 ds_read_b128 lands at 2-way aliasing (free).
__device__ __forceinline__ int swz128(int byteoff) {
  return byteoff ^ (((byteoff >> 7) & 7) << 4);
}

// ------------------------------------------------------------------
// Tiled transpose f32 -> bf16.
// ------------------------------------------------------------------
__global__ void tr_f32_bf16(const float* __restrict__ src, u16* __restrict__ dst,
                            int R, int Cc, long long sb, long long db, int dld) {
  __shared__ float t[32][33];
  const int bz = blockIdx.z;
  const int r0 = blockIdx.y * 32, c0 = blockIdx.x * 32;
  const int tx = threadIdx.x, ty = threadIdx.y;
  const float* s = src + bz * sb;
  u16* d = dst + bz * db;
#pragma unroll
  for (int i = 0; i < 4; i++)
    t[ty + i * 8][tx] = s[(size_t)(r0 + ty + i * 8) * Cc + c0 + tx];
  __syncthreads();
#pragma unroll
  for (int i = 0; i < 4; i++)
    d[(size_t)(c0 + ty + i * 8) * dld + r0 + tx] = f2bf(t[tx][ty + i * 8]);
}

// bf16 -> bf16 transpose (for V)
__global__ void tr_bf16(const u16* __restrict__ src, u16* __restrict__ dst,
                        int R, int Cc, long long sb, long long db, int dld) {
  __shared__ u16 t[32][33];
  const int bz = blockIdx.z;
  const int r0 = blockIdx.y * 32, c0 = blockIdx.x * 32;
  const int tx = threadIdx.x, ty = threadIdx.y;
  const u16* s = src + bz * sb;
  u16* d = dst + bz * db;
#pragma unroll
  for (int i = 0; i < 4; i++)
    t[ty + i * 8][tx] = s[(size_t)(r0 + ty + i * 8) * Cc + c0 + tx];
  __syncthreads();
#pragma unroll
  for (int i = 0; i < 4; i++)
    d[(size_t)(c0 + ty + i * 8) * dld + r0 + tx] = t[tx][ty + i * 8];
}

// ------------------------------------------------------------------
// LayerNorm: one block (256 thr) per row of [4096][1024] f32 -> bf16
// ------------------------------------------------------------------
__global__ __launch_bounds__(256) void ln_kernel(
    const float* __restrict__ x, const float* __restrict__ w,
    const float* __restrict__ b, u16* __restrict__ y) {
  const int row = blockIdx.x, tid = threadIdx.x;
  const float4 v = reinterpret_cast<const float4*>(x + (size_t)row * CC)[tid];
  float s = v.x + v.y + v.z + v.w;
  float s2 = v.x * v.x + v.y * v.y + v.z * v.z + v.w * v.w;
#pragma unroll
  for (int off = 32; off >= 1; off >>= 1) {
    s += __shfl_xor(s, off);
    s2 += __shfl_xor(s2, off);
  }
  __shared__ float ps[4], ps2[4];
  const int wave = tid >> 6, lane = tid & 63;
  if (lane == 0) { ps[wave] = s; ps2[wave] = s2; }
  __syncthreads();
  s = ps[0] + ps[1] + ps[2] + ps[3];
  s2 = ps2[0] + ps2[1] + ps2[2] + ps2[3];
  const float mu = s * (1.f / CC);
  const float rstd = rsqrtf(s2 * (1.f / CC) - mu * mu + 1e-5f);
  const float4 wv = reinterpret_cast<const float4*>(w)[tid];
  const float4 bv = reinterpret_cast<const float4*>(b)[tid];
  ushort4 o;
  o.x = f2bf((v.x - mu) * rstd * wv.x + bv.x);
  o.y = f2bf((v.y - mu) * rstd * wv.y + bv.y);
  o.z = f2bf((v.z - mu) * rstd * wv.z + bv.z);
  o.w = f2bf((v.w - mu) * rstd * wv.w + bv.w);
  reinterpret_cast<ushort4*>(y + (size_t)row * CC)[tid] = o;
}

// ------------------------------------------------------------------
// 128x128 bf16 MFMA GEMM core (m97-style).  A [M][K], Bt [N][K] row-major.
// ------------------------------------------------------------------
__device__ __forceinline__ void gemm128_core(
    const u16* __restrict__ A, const u16* __restrict__ Bt, int K,
    f4 (&acc)[4][4]) {
  __shared__ u16 As[128 * 32];
  __shared__ u16 Bs[128 * 32];
  const int tid = threadIdx.x;
  const int wave = tid >> 6, lane = tid & 63;
  const int wm = wave >> 1, wn = wave & 1;
  const int lg = lane >> 4, ll = lane & 15;

  const u16* ga = A + (size_t)(blockIdx.y * 128 + (tid >> 2)) * K + (tid & 3) * 8;
  const u16* gb = Bt + (size_t)(blockIdx.x * 128 + (tid >> 2)) * K + (tid & 3) * 8;
  u16* la = As + tid * 8;
  u16* lb = Bs + tid * 8;
  const size_t g64 = (size_t)64 * K;

  for (int kt = 0; kt < K; kt += 32) {
    __builtin_amdgcn_global_load_lds(AS1(ga), AS3(la), 16, 0, 0);
    __builtin_amdgcn_global_load_lds(AS1(ga + g64), AS3(la + 2048), 16, 0, 0);
    __builtin_amdgcn_global_load_lds(AS1(gb), AS3(lb), 16, 0, 0);
    __builtin_amdgcn_global_load_lds(AS1(gb + g64), AS3(lb + 2048), 16, 0, 0);
    __syncthreads();
    bfrag af[4], bf[4];
#pragma unroll
    for (int i = 0; i < 4; i++) {
      af[i] = *(const bfrag*)&As[(wm * 64 + i * 16 + ll) * 32 + lg * 8];
      bf[i] = *(const bfrag*)&Bs[(wn * 64 + i * 16 + ll) * 32 + lg * 8];
    }
#pragma unroll
    for (int i = 0; i < 4; i++)
#pragma unroll
      for (int j = 0; j < 4; j++)
        acc[i][j] = __builtin_amdgcn_mfma_f32_16x16x32_bf16(af[i], bf[j], acc[i][j], 0, 0, 0);
    __syncthreads();
    ga += 32; gb += 32;
  }
}

// C/D frag mapping (verified m89): col = lane&15, row = (lane>>4)*4 + r
#define EPI_COORDS                                              \
  const int tid = threadIdx.x;                                  \
  const int wave = tid >> 6, lane = tid & 63;                   \
  const int wm = wave >> 1, wn = wave & 1;                      \
  const int lg = lane >> 4, ll = lane & 15;

// QKV: N=3072 (q|k|v), bias add, fold 1/32 into q, scatter to [BH][T][HS]
__global__ __launch_bounds__(256, 2) void gemm_qkv(
    const u16* __restrict__ A, const u16* __restrict__ Bt,
    const float* __restrict__ bq, const float* __restrict__ bk,
    const float* __restrict__ bv,
    u16* __restrict__ q, u16* __restrict__ k, u16* __restrict__ v) {
  f4 acc[4][4] = {};
  gemm128_core(A, Bt, CC, acc);
  EPI_COORDS
#pragma unroll
  for (int j = 0; j < 4; j++) {
    const int n = blockIdx.x * 128 + wn * 64 + j * 16 + ll;
    const int sec = n >> 10, nn = n & 1023, h = nn >> 6, d = nn & 63;
    const float bias = (sec == 0 ? bq : (sec == 1 ? bk : bv))[nn];
    const float scale = (sec == 0) ? 0.03125f : 1.0f;  // C^-0.5 folded into Q
    u16* dst = sec == 0 ? q : (sec == 1 ? k : v);
#pragma unroll
    for (int i = 0; i < 4; i++)
#pragma unroll
      for (int r = 0; r < 4; r++) {
        const int m = blockIdx.y * 128 + wm * 64 + i * 16 + lg * 4 + r;
        const int b = m >> 11, t = m & 2047;
        dst[(((size_t)b * HH + h) * TT + t) * HS + d] = f2bf((acc[i][j][r] + bias) * scale);
      }
  }
}

// PROJ: out = x + (A @ Wp + bp) -> f32 out buffer (= d_out)
__global__ __launch_bounds__(256, 2) void gemm_proj(
    const u16* __restrict__ A, const u16* __restrict__ Bt,
    const float* __restrict__ bp, const float* __restrict__ x,
    float* __restrict__ outw) {
  f4 acc[4][4] = {};
  gemm128_core(A, Bt, CC, acc);
  EPI_COORDS
#pragma unroll
  for (int i = 0; i < 4; i++)
#pragma unroll
    for (int j = 0; j < 4; j++) {
      const int n = blockIdx.x * 128 + wn * 64 + j * 16 + ll;
      const float bias = bp[n];
#pragma unroll
      for (int r = 0; r < 4; r++) {
        const int m = blockIdx.y * 128 + wm * 64 + i * 16 + lg * 4 + r;
        const size_t idx = (size_t)m * CC + n;
        outw[idx] = acc[i][j][r] + bias + x[idx];
      }
    }
}

// FFN1: h = gelu_exact(A @ W1 + b1) -> bf16 [4096][4096]
__global__ __launch_bounds__(256, 2) void gemm_ffn1(
    const u16* __restrict__ A, const u16* __restrict__ Bt,
    const float* __restrict__ b1, u16* __restrict__ hb) {
  f4 acc[4][4] = {};
  gemm128_core(A, Bt, CC, acc);
  EPI_COORDS
#pragma unroll
  for (int i = 0; i < 4; i++)
#pragma unroll
    for (int j = 0; j < 4; j++) {
      const int n = blockIdx.x * 128 + wn * 64 + j * 16 + ll;
      const float bias = b1[n];
#pragma unroll
      for (int r = 0; r < 4; r++) {
        const int m = blockIdx.y * 128 + wm * 64 + i * 16 + lg * 4 + r;
        const float t = acc[i][j][r] + bias;
        const float g = 0.5f * t * (1.0f + erff(t * 0.70710678118654752f));
        hb[(size_t)m * FF + n] = f2bf(g);
      }
    }
}

// FFN2: d_out = outw + (A @ W2 + b2)   (outw aliases d_out; same-index RMW)
__global__ __launch_bounds__(256, 2) void gemm_ffn2(
    const u16* __restrict__ A, const u16* __restrict__ Bt,
    const float* __restrict__ b2, const float* __restrict__ outw,
    float* __restrict__ dout) {
  f4 acc[4][4] = {};
  gemm128_core(A, Bt, FF, acc);
  EPI_COORDS
#pragma unroll
  for (int i = 0; i < 4; i++)
#pragma unroll
    for (int j = 0; j < 4; j++) {
      const int n = blockIdx.x * 128 + wn * 64 + j * 16 + ll;
      const float bias = b2[n];
#pragma unroll
      for (int r = 0; r < 4; r++) {
        const int m = blockIdx.y * 128 + wm * 64 + i * 16 + lg * 4 + r;
        const size_t idx = (size_t)m * CC + n;
        dout[idx] = acc[i][j][r] + bias + outw[idx];
      }
    }
}

// ------------------------------------------------------------------
// Flash attention fwd, v3: SWAPPED-OPERAND QK^T (S^T = mfma(K,Q)) so each
// lane owns one q-row's P values -> row max/sum are lane-local + 2 shuffles.
// P packed to bf16 pairs (compiler cvt_pk) -> wave-private LDS ds_write_b64,
// read back as B-frags for O^T = mfma(V^T, P).  K/V staging identical to v2:
// KVBLK=64, XOR-swizzled, double-buffered, counted vmcnt across raw barriers.
// Q,K: [32][2048][64] bf16 (Q pre-scaled), Vt: [32][64][2048] bf16.
// grid (16 q-tiles, 32 bh), 256 thr (4 waves), 32 q-rows/wave.
// LDS: 2*8 (K) + 2*8 (V) + 16 (P) = 48 KB.
// ------------------------------------------------------------------
__global__ __launch_bounds__(256, 2) void attn_kernel(
    const u16* __restrict__ Q, const u16* __restrict__ Kb,
    const u16* __restrict__ Vt, u16* __restrict__ Ao) {
  __shared__ __align__(1024) u16 Ks[2][64 * 64];  // [s:64][d:64], swizzled
  __shared__ __align__(1024) u16 Vs[2][64 * 64];  // [d:64][s:64], swizzled
  __shared__ __align__(1024) u16 Ps[4][32 * 64];  // per-wave [q:32][s:64], swizzled
  const int bh = blockIdx.y, qt = blockIdx.x;
  const int tid = threadIdx.x, wave = tid >> 6, lane = tid & 63;
  const int lg = lane >> 4, ll = lane & 15;

  // Q fragments as MFMA *B*-operand: lane ll holds Q row (qb*16+ll), d contig
  bfrag qf[2][2];
  const u16* Qb = Q + ((size_t)bh * TT + qt * 128 + wave * 32) * HS;
#pragma unroll
  for (int qb = 0; qb < 2; qb++)
#pragma unroll
    for (int dc = 0; dc < 2; dc++)
      qf[qb][dc] = *(const bfrag*)&Qb[(qb * 16 + ll) * HS + dc * 32 + lg * 8];

  // O^T accumulators: lane holds q = ll (col), d = fo*16 + lg*4 + r (row)
  f4 o[2][4] = {};
  float mrun[2] = {-INFINITY, -INFINITY}, lrun[2] = {0.f, 0.f};

  // staging: dest is LINEAR (global_load_lds writes base+lane*16); the
  // SOURCE chunk index is pre-swizzled so that swizzled reads see row-major.
  const int trow = tid >> 3;                 // dest row within 32-row half
  const int tch  = (tid & 7) ^ (trow & 7);   // pre-swizzled source chunk
  const u16* gk = Kb + ((size_t)bh * TT + trow) * HS + tch * 8;
  const u16* gv = Vt + ((size_t)bh * HS + trow) * TT + tch * 8;

  char* const pw = (char*)Ps[wave];

#define STAGE(bufi, stt)                                                          \
  do {                                                                            \
    u16* lk = &Ks[bufi][tid * 8];                                                 \
    u16* lv = &Vs[bufi][tid * 8];                                                 \
    __builtin_amdgcn_global_load_lds(AS1(gk + (size_t)(stt) * HS), AS3(lk), 16, 0, 0); \
    __builtin_amdgcn_global_load_lds(AS1(gk + (size_t)(stt) * HS + 32 * HS), AS3(lk + 2048), 16, 0, 0); \
    __builtin_amdgcn_global_load_lds(AS1(gv + (stt)), AS3(lv), 16, 0, 0);         \
    __builtin_amdgcn_global_load_lds(AS1(gv + (stt) + (size_t)32 * TT), AS3(lv + 2048), 16, 0, 0); \
  } while (0)

  STAGE(0, 0);
  int cur = 0;

  for (int st = 0; st < TT; st += 64) {
    if (st + 64 < TT) {
      STAGE(cur ^ 1, st + 64);
      asm volatile("s_waitcnt vmcnt(4)" ::: "memory");  // cur ready, next in flight
    } else {
      asm volatile("s_waitcnt vmcnt(0)" ::: "memory");
    }
    __builtin_amdgcn_s_barrier();
    __builtin_amdgcn_sched_barrier(0);

    const char* kbuf = (const char*)Ks[cur];
    const char* vbuf = (const char*)Vs[cur];

    // S^T = K Q^T : lane (lg,ll) holds S[q = ll][k = kb*16 + lg*4 + r]
    f4 p[2][4];
#pragma unroll
    for (int kb = 0; kb < 4; kb++) {
      const int row = kb * 16 + ll;
      const bfrag k0 = *(const bfrag*)(kbuf + swz128(row * 128 + lg * 16));
      const bfrag k1 = *(const bfrag*)(kbuf + swz128(row * 128 + 64 + lg * 16));
#pragma unroll
      for (int qb = 0; qb < 2; qb++) {
        f4 z = {0.f, 0.f, 0.f, 0.f};
        z = __builtin_amdgcn_mfma_f32_16x16x32_bf16(k0, qf[qb][0], z, 0, 0, 0);
        p[qb][kb] = __builtin_amdgcn_mfma_f32_16x16x32_bf16(k1, qf[qb][1], z, 0, 0, 0);
      }
    }

    // online softmax: per-lane over 16 values + 2 cross-group shuffles
#pragma unroll
    for (int qb = 0; qb < 2; qb++) {
      float pm = p[qb][0][0];
#pragma unroll
      for (int kb = 0; kb < 4; kb++)
#pragma unroll
        for (int r = 0; r < 4; r++)
          if (kb | r) pm = fmaxf(pm, p[qb][kb][r]);
      pm = fmaxf(pm, __shfl_xor(pm, 16));
      pm = fmaxf(pm, __shfl_xor(pm, 32));
      const float mn = fmaxf(mrun[qb], pm);
      const float al = __expf(mrun[qb] - mn);
      mrun[qb] = mn;
      float rs = 0.f;
#pragma unroll
      for (int kb = 0; kb < 4; kb++)
#pragma unroll
        for (int r = 0; r < 4; r++) {
          const float e = __expf(p[qb][kb][r] - mn);
          p[qb][kb][r] = e;
          rs += e;
        }
      rs += __shfl_xor(rs, 16);
      rs += __shfl_xor(rs, 32);
      lrun[qb] = lrun[qb] * al + rs;
#pragma unroll
      for (int fo = 0; fo < 4; fo++) o[qb][fo] *= al;
      // P -> wave-private LDS as bf16 pairs (8B swizzled writes).
      // Row q^ = qb*16+ll, cols k = kb*16 + lg*4 + 0..3.
#pragma unroll
      for (int kb = 0; kb < 4; kb++) {
        union { uint2 v; __bf16 h[4]; } w;
        w.h[0] = (__bf16)p[qb][kb][0];
        w.h[1] = (__bf16)p[qb][kb][1];
        w.h[2] = (__bf16)p[qb][kb][2];
        w.h[3] = (__bf16)p[qb][kb][3];
        *(uint2*)(pw + swz128((qb * 16 + ll) * 128 + kb * 32 + lg * 8)) = w.v;
      }
    }

    // O^T += V^T P : A = V^T rows (d), B = P rows (q).  Wave-private P, no barrier.
#pragma unroll
    for (int ks = 0; ks < 2; ks++) {
      const bfrag pb0 = *(const bfrag*)(pw + swz128(ll * 128 + ks * 64 + lg * 16));
      const bfrag pb1 = *(const bfrag*)(pw + swz128((16 + ll) * 128 + ks * 64 + lg * 16));
#pragma unroll
      for (int fo = 0; fo < 4; fo++) {
        const bfrag vf = *(const bfrag*)(vbuf + swz128((fo * 16 + ll) * 128 + ks * 64 + lg * 16));
        o[0][fo] = __builtin_amdgcn_mfma_f32_16x16x32_bf16(vf, pb0, o[0][fo], 0, 0, 0);
        o[1][fo] = __builtin_amdgcn_mfma_f32_16x16x32_bf16(vf, pb1, o[1][fo], 0, 0, 0);
      }
    }

    __builtin_amdgcn_sched_barrier(0);
    __builtin_amdgcn_s_barrier();  // all waves done reading buf[cur] before restage
    cur ^= 1;
  }
#undef STAGE

  // epilogue: O^T / l -> [B*T][C] bf16.  lane writes q = ll, d = fo*16+lg*4+0..3
  const int b = bh >> 4, h = bh & 15;
#pragma unroll
  for (int qb = 0; qb < 2; qb++) {
    const float inv = 1.0f / lrun[qb];
    const int t = qt * 128 + wave * 32 + qb * 16 + ll;
#pragma unroll
    for (int fo = 0; fo < 4; fo++) {
      union { uint2 v; __bf16 h[4]; } w;
      w.h[0] = (__bf16)(o[qb][fo][0] * inv);
      w.h[1] = (__bf16)(o[qb][fo][1] * inv);
      w.h[2] = (__bf16)(o[qb][fo][2] * inv);
      w.h[3] = (__bf16)(o[qb][fo][3] * inv);
      *(uint2*)&Ao[((size_t)b * TT + t) * CC + h * HS + fo * 16 + lg * 4] = w.v;
    }
  }
}

// ------------------------------------------------------------------
extern "C" void kernel_launch(void* const* d_in, const int* in_sizes, int n_in,
                              void* d_out, int out_size, void* d_ws, size_t ws_size,
                              hipStream_t stream) {
  const float* x    = (const float*)d_in[0];
  const float* Wq   = (const float*)d_in[1];
  const float* bq   = (const float*)d_in[2];
  const float* Wk   = (const float*)d_in[3];
  const float* bk   = (const float*)d_in[4];
  const float* Wv   = (const float*)d_in[5];
  const float* bv   = (const float*)d_in[6];
  const float* Wp   = (const float*)d_in[7];
  const float* bp   = (const float*)d_in[8];
  const float* W1   = (const float*)d_in[9];
  const float* b1   = (const float*)d_in[10];
  const float* W2   = (const float*)d_in[11];
  const float* b2   = (const float*)d_in[12];
  const float* ln1w = (const float*)d_in[13];
  const float* ln1b = (const float*)d_in[14];
  const float* ln2w = (const float*)d_in[15];
  const float* ln2b = (const float*)d_in[16];
  float* dout = (float*)d_out;

  char* ws = (char*)d_ws;
  u16* wqkv = (u16*)(ws + 0);          // [3072][1024]  6.29 MB
  u16* wpt  = (u16*)(ws + 6291456);    // [1024][1024]  2.10 MB
  u16* w1t  = (u16*)(ws + 8388608);    // [4096][1024]  8.39 MB
  u16* w2t  = (u16*)(ws + 16777216);   // [1024][4096]  8.39 MB
  u16* xn   = (u16*)(ws + 25165824);   // [4096][1024]  8.39 MB (reused as LN2 out)
  u16* qb   = (u16*)(ws + 33554432);   // [32][2048][64]
  u16* kb   = (u16*)(ws + 41943040);
  u16* vb   = (u16*)(ws + 50331648);
  u16* vt   = (u16*)(ws + 58720256);   // [32][64][2048]
  u16* ao   = (u16*)(ws + 67108864);   // [4096][1024]
  u16* hb   = qb;                      // FFN hidden overlays q/k/v/vt (33.55 MB)

  dim3 blk256(256);
  dim3 blkT(32, 8);

  // weight prep: transpose to [N][K] bf16
  tr_f32_bf16<<<dim3(2, 32, 16), blkT, 0, stream>>>(Wq, wqkv,               1024,   64, 65536LL, 65536LL, 1024);
  tr_f32_bf16<<<dim3(2, 32, 16), blkT, 0, stream>>>(Wk, wqkv + 1024 * 1024, 1024,   64, 65536LL, 65536LL, 1024);
  tr_f32_bf16<<<dim3(2, 32, 16), blkT, 0, stream>>>(Wv, wqkv + 2048 * 1024, 1024,   64, 65536LL, 65536LL, 1024);
  tr_f32_bf16<<<dim3(32, 32, 1),  blkT, 0, stream>>>(Wp, wpt, 1024, 1024, 0LL, 0LL, 1024);
  tr_f32_bf16<<<dim3(128, 32, 1), blkT, 0, stream>>>(W1, w1t, 1024, 4096, 0LL, 0LL, 1024);
  tr_f32_bf16<<<dim3(32, 128, 1), blkT, 0, stream>>>(W2, w2t, 4096, 1024, 0LL, 0LL, 4096);

  // LN1 -> xn (bf16)
  ln_kernel<<<dim3(MT), blk256, 0, stream>>>(x, ln1w, ln1b, xn);

  // QKV projection (q pre-scaled by C^-0.5)
  gemm_qkv<<<dim3(24, 32), blk256, 0, stream>>>(xn, wqkv, bq, bk, bv, qb, kb, vb);

  // V -> Vt [bh][64][2048]
  tr_bf16<<<dim3(2, 64, 32), blkT, 0, stream>>>(vb, vt, 2048, 64, 131072LL, 131072LL, 2048);

  // attention
  attn_kernel<<<dim3(16, 32), blk256, 0, stream>>>(qb, kb, vt, ao);

  // out = x + ao @ Wp + bp   (f32, into d_out)
  gemm_proj<<<dim3(8, 32), blk256, 0, stream>>>(ao, wpt, bp, x, dout);

  // LN2 -> xn (reuse)
  ln_kernel<<<dim3(MT), blk256, 0, stream>>>(dout, ln2w, ln2b, xn);

  // FFN
  gemm_ffn1<<<dim3(32, 32), blk256, 0, stream>>>(xn, w1t, b1, hb);
  gemm_ffn2<<<dim3(8, 32), blk256, 0, stream>>>(hb, w2t, b2, dout, dout);
}

// Round 5
// 292.047 us; speedup vs baseline: 1.2123x; 1.0204x over previous
//
#include <hip/hip_runtime.h>
#include <math.h>

// ---- problem dims (B=2, T=2048, C=1024, H=16, HS=64) ----
#define BB 2
#define TT 2048
#define CC 1024
#define HH 16
#define HS 64
#define MT 4096   // B*T
#define FF 4096   // 4*C

typedef unsigned short u16;
typedef __bf16 bfrag __attribute__((ext_vector_type(8)));
typedef float f4 __attribute__((ext_vector_type(4)));

#define AS1(p) ((const __attribute__((address_space(1))) void*)(p))
#define AS3(p) ((__attribute__((address_space(3))) void*)(p))

__device__ __forceinline__ u16 f2bf(float f) {
  union { float f; unsigned u; } a; a.f = f;
  return (u16)((a.u + 0x7fffu + ((a.u >> 16) & 1u)) >> 16);
}

// XOR-swizzle for 128-byte-row LDS tiles (attention): spreads 8 rows over
// 8 distinct 16B slots.
__device__ __forceinline__ int swz128(int byteoff) {
  return byteoff ^ (((byteoff >> 7) & 7) << 4);
}

// XOR-swizzle for 64-byte-row LDS tiles (GEMM A/B, row = 32 u16):
// chunk ^= (row>>1)&3.  Read pattern (16 rows x 4 chunks per ds_read_b128)
// goes 8-way -> 2-way (free).
__device__ __forceinline__ int swzAB(int byteoff) {
  return byteoff ^ (((byteoff >> 7) & 3) << 4);
}

// ------------------------------------------------------------------
// Tiled transpose f32 -> bf16.
// ------------------------------------------------------------------
__global__ void tr_f32_bf16(const float* __restrict__ src, u16* __restrict__ dst,
                            int R, int Cc, long long sb, long long db, int dld) {
  __shared__ float t[32][33];
  const int bz = blockIdx.z;
  const int r0 = blockIdx.y * 32, c0 = blockIdx.x * 32;
  const int tx = threadIdx.x, ty = threadIdx.y;
  const float* s = src + bz * sb;
  u16* d = dst + bz * db;
#pragma unroll
  for (int i = 0; i < 4; i++)
    t[ty + i * 8][tx] = s[(size_t)(r0 + ty + i * 8) * Cc + c0 + tx];
  __syncthreads();
#pragma unroll
  for (int i = 0; i < 4; i++)
    d[(size_t)(c0 + ty + i * 8) * dld + r0 + tx] = f2bf(t[tx][ty + i * 8]);
}

// bf16 -> bf16 transpose (for V)
__global__ void tr_bf16(const u16* __restrict__ src, u16* __restrict__ dst,
                        int R, int Cc, long long sb, long long db, int dld) {
  __shared__ u16 t[32][33];
  const int bz = blockIdx.z;
  const int r0 = blockIdx.y * 32, c0 = blockIdx.x * 32;
  const int tx = threadIdx.x, ty = threadIdx.y;
  const u16* s = src + bz * sb;
  u16* d = dst + bz * db;
#pragma unroll
  for (int i = 0; i < 4; i++)
    t[ty + i * 8][tx] = s[(size_t)(r0 + ty + i * 8) * Cc + c0 + tx];
  __syncthreads();
#pragma unroll
  for (int i = 0; i < 4; i++)
    d[(size_t)(c0 + ty + i * 8) * dld + r0 + tx] = t[tx][ty + i * 8];
}

// ------------------------------------------------------------------
// LayerNorm: one block (256 thr) per row of [4096][1024] f32 -> bf16
// ------------------------------------------------------------------
__global__ __launch_bounds__(256) void ln_kernel(
    const float* __restrict__ x, const float* __restrict__ w,
    const float* __restrict__ b, u16* __restrict__ y) {
  const int row = blockIdx.x, tid = threadIdx.x;
  const float4 v = reinterpret_cast<const float4*>(x + (size_t)row * CC)[tid];
  float s = v.x + v.y + v.z + v.w;
  float s2 = v.x * v.x + v.y * v.y + v.z * v.z + v.w * v.w;
#pragma unroll
  for (int off = 32; off >= 1; off >>= 1) {
    s += __shfl_xor(s, off);
    s2 += __shfl_xor(s2, off);
  }
  __shared__ float ps[4], ps2[4];
  const int wave = tid >> 6, lane = tid & 63;
  if (lane == 0) { ps[wave] = s; ps2[wave] = s2; }
  __syncthreads();
  s = ps[0] + ps[1] + ps[2] + ps[3];
  s2 = ps2[0] + ps2[1] + ps2[2] + ps2[3];
  const float mu = s * (1.f / CC);
  const float rstd = rsqrtf(s2 * (1.f / CC) - mu * mu + 1e-5f);
  const float4 wv = reinterpret_cast<const float4*>(w)[tid];
  const float4 bv = reinterpret_cast<const float4*>(b)[tid];
  ushort4 o;
  o.x = f2bf((v.x - mu) * rstd * wv.x + bv.x);
  o.y = f2bf((v.y - mu) * rstd * wv.y + bv.y);
  o.z = f2bf((v.z - mu) * rstd * wv.z + bv.z);
  o.w = f2bf((v.w - mu) * rstd * wv.w + bv.w);
  reinterpret_cast<ushort4*>(y + (size_t)row * CC)[tid] = o;
}

// ------------------------------------------------------------------
// GEMM core v2: 128 x (NJ*32) tile, depth-3 software pipeline.
// 3 LDS buffers, raw barriers, counted vmcnt (loads in flight across
// barriers), XOR-swizzled LDS (both-sides), setprio around MFMA.
// A [M][K], Bt [N][K] row-major bf16.  256 thr = 4 waves (2x2),
// wave computes 64 x (NJ*16).
// ------------------------------------------------------------------
template<int NJ>  // 4 -> BN=128 (L=4 loads/stage), 2 -> BN=64 (L=3)
__device__ __forceinline__ void gemm_core(
    const u16* __restrict__ A, const u16* __restrict__ Bt, int K,
    f4 (&acc)[4][NJ]) {
  constexpr int BN = NJ * 32;
  __shared__ u16 As[3][128 * 32];
  __shared__ u16 Bs[3][BN * 32];
  const int tid = threadIdx.x;
  const int wave = tid >> 6, lane = tid & 63;
  const int wm = wave >> 1, wn = wave & 1;
  const int lg = lane >> 4, ll = lane & 15;

  // staging: LINEAR dest (global_load_lds), pre-swizzled source chunk so
  // swizzled ds_reads decode row-major (rule: both-sides-or-neither).
  const int trow = tid >> 2;                      // 0..63
  const int tch  = (tid & 3) ^ ((trow >> 1) & 3); // source chunk
  const u16* ga = A + (size_t)(blockIdx.y * 128 + trow) * K + tch * 8;
  const u16* gb = Bt + (size_t)(blockIdx.x * BN + trow) * K + tch * 8;
  const size_t g64 = (size_t)64 * K;
  const int nt = K >> 5;

  auto GSTAGE = [&](int bi, int kt) {
    u16* la = &As[bi][tid * 8];
    u16* lb = &Bs[bi][tid * 8];
    const u16* gA = ga + kt * 32;
    const u16* gB = gb + kt * 32;
    __builtin_amdgcn_global_load_lds(AS1(gA), AS3(la), 16, 0, 0);
    __builtin_amdgcn_global_load_lds(AS1(gA + g64), AS3(la + 2048), 16, 0, 0);
    __builtin_amdgcn_global_load_lds(AS1(gB), AS3(lb), 16, 0, 0);
    if constexpr (NJ == 4)
      __builtin_amdgcn_global_load_lds(AS1(gB + g64), AS3(lb + 2048), 16, 0, 0);
  };

  GSTAGE(0, 0);
  GSTAGE(1, 1);
  GSTAGE(2, 2);
  int bi = 0;
  for (int t = 0; t < nt; t++) {
    const int ahead = nt - 1 - t;   // tiles staged beyond t (max 2)
    if constexpr (NJ == 4) {
      if (ahead >= 2)      asm volatile("s_waitcnt vmcnt(8)" ::: "memory");
      else if (ahead == 1) asm volatile("s_waitcnt vmcnt(4)" ::: "memory");
      else                 asm volatile("s_waitcnt vmcnt(0)" ::: "memory");
    } else {
      if (ahead >= 2)      asm volatile("s_waitcnt vmcnt(6)" ::: "memory");
      else if (ahead == 1) asm volatile("s_waitcnt vmcnt(3)" ::: "memory");
      else                 asm volatile("s_waitcnt vmcnt(0)" ::: "memory");
    }
    __builtin_amdgcn_s_barrier();      // tile t visible to all waves
    __builtin_amdgcn_sched_barrier(0);

    const char* as_ = (const char*)As[bi];
    const char* bs_ = (const char*)Bs[bi];
    bfrag af[4], bf[NJ];
#pragma unroll
    for (int i = 0; i < 4; i++)
      af[i] = *(const bfrag*)(as_ + swzAB((wm * 64 + i * 16 + ll) * 64 + lg * 16));
#pragma unroll
    for (int j = 0; j < NJ; j++)
      bf[j] = *(const bfrag*)(bs_ + swzAB((wn * (BN / 2) + j * 16 + ll) * 64 + lg * 16));

    __builtin_amdgcn_s_setprio(1);
#pragma unroll
    for (int i = 0; i < 4; i++)
#pragma unroll
      for (int j = 0; j < NJ; j++)
        acc[i][j] = __builtin_amdgcn_mfma_f32_16x16x32_bf16(af[i], bf[j], acc[i][j], 0, 0, 0);
    __builtin_amdgcn_s_setprio(0);

    __builtin_amdgcn_sched_barrier(0);
    __builtin_amdgcn_s_barrier();      // all waves done reading buf[bi]
    if (t + 3 < nt) GSTAGE(bi, t + 3);
    bi = (bi == 2) ? 0 : bi + 1;
  }
}

// C/D frag mapping (verified m89): col = lane&15, row = (lane>>4)*4 + r
#define EPI_COORDS                                              \
  const int tid = threadIdx.x;                                  \
  const int wave = tid >> 6, lane = tid & 63;                   \
  const int wm = wave >> 1, wn = wave & 1;                      \
  const int lg = lane >> 4, ll = lane & 15;

// QKV: N=3072 (q|k|v), bias add, fold 1/32 into q, scatter to [BH][T][HS]
__global__ __launch_bounds__(256, 2) void gemm_qkv(
    const u16* __restrict__ A, const u16* __restrict__ Bt,
    const float* __restrict__ bq, const float* __restrict__ bk,
    const float* __restrict__ bv,
    u16* __restrict__ q, u16* __restrict__ k, u16* __restrict__ v) {
  f4 acc[4][4] = {};
  gemm_core<4>(A, Bt, CC, acc);
  EPI_COORDS
#pragma unroll
  for (int j = 0; j < 4; j++) {
    const int n = blockIdx.x * 128 + wn * 64 + j * 16 + ll;
    const int sec = n >> 10, nn = n & 1023, h = nn >> 6, d = nn & 63;
    const float bias = (sec == 0 ? bq : (sec == 1 ? bk : bv))[nn];
    const float scale = (sec == 0) ? 0.03125f : 1.0f;  // C^-0.5 folded into Q
    u16* dst = sec == 0 ? q : (sec == 1 ? k : v);
#pragma unroll
    for (int i = 0; i < 4; i++)
#pragma unroll
      for (int r = 0; r < 4; r++) {
        const int m = blockIdx.y * 128 + wm * 64 + i * 16 + lg * 4 + r;
        const int b = m >> 11, t = m & 2047;
        dst[(((size_t)b * HH + h) * TT + t) * HS + d] = f2bf((acc[i][j][r] + bias) * scale);
      }
  }
}

// PROJ: out = x + (A @ Wp + bp) -> f32 out buffer (= d_out).  BN=64.
__global__ __launch_bounds__(256, 2) void gemm_proj(
    const u16* __restrict__ A, const u16* __restrict__ Bt,
    const float* __restrict__ bp, const float* __restrict__ x,
    float* __restrict__ outw) {
  f4 acc[4][2] = {};
  gemm_core<2>(A, Bt, CC, acc);
  EPI_COORDS
#pragma unroll
  for (int i = 0; i < 4; i++)
#pragma unroll
    for (int j = 0; j < 2; j++) {
      const int n = blockIdx.x * 64 + wn * 32 + j * 16 + ll;
      const float bias = bp[n];
#pragma unroll
      for (int r = 0; r < 4; r++) {
        const int m = blockIdx.y * 128 + wm * 64 + i * 16 + lg * 4 + r;
        const size_t idx = (size_t)m * CC + n;
        outw[idx] = acc[i][j][r] + bias + x[idx];
      }
    }
}

// FFN1: h = gelu_exact(A @ W1 + b1) -> bf16 [4096][4096]
__global__ __launch_bounds__(256, 2) void gemm_ffn1(
    const u16* __restrict__ A, const u16* __restrict__ Bt,
    const float* __restrict__ b1, u16* __restrict__ hb) {
  f4 acc[4][4] = {};
  gemm_core<4>(A, Bt, CC, acc);
  EPI_COORDS
#pragma unroll
  for (int i = 0; i < 4; i++)
#pragma unroll
    for (int j = 0; j < 4; j++) {
      const int n = blockIdx.x * 128 + wn * 64 + j * 16 + ll;
      const float bias = b1[n];
#pragma unroll
      for (int r = 0; r < 4; r++) {
        const int m = blockIdx.y * 128 + wm * 64 + i * 16 + lg * 4 + r;
        const float t = acc[i][j][r] + bias;
        const float g = 0.5f * t * (1.0f + erff(t * 0.70710678118654752f));
        hb[(size_t)m * FF + n] = f2bf(g);
      }
    }
}

// FFN2: d_out = outw + (A @ W2 + b2)   (outw aliases d_out).  BN=64.
__global__ __launch_bounds__(256, 2) void gemm_ffn2(
    const u16* __restrict__ A, const u16* __restrict__ Bt,
    const float* __restrict__ b2, const float* __restrict__ outw,
    float* __restrict__ dout) {
  f4 acc[4][2] = {};
  gemm_core<2>(A, Bt, FF, acc);
  EPI_COORDS
#pragma unroll
  for (int i = 0; i < 4; i++)
#pragma unroll
    for (int j = 0; j < 2; j++) {
      const int n = blockIdx.x * 64 + wn * 32 + j * 16 + ll;
      const float bias = b2[n];
#pragma unroll
      for (int r = 0; r < 4; r++) {
        const int m = blockIdx.y * 128 + wm * 64 + i * 16 + lg * 4 + r;
        const size_t idx = (size_t)m * CC + n;
        dout[idx] = acc[i][j][r] + bias + outw[idx];
      }
    }
}

// ------------------------------------------------------------------
// Flash attention fwd, v3 (unchanged from round 3): swapped-operand QK^T,
// lane-local softmax, wave-private P, double-buffered K/V, counted vmcnt.
// ------------------------------------------------------------------
__global__ __launch_bounds__(256, 2) void attn_kernel(
    const u16* __restrict__ Q, const u16* __restrict__ Kb,
    const u16* __restrict__ Vt, u16* __restrict__ Ao) {
  __shared__ __align__(1024) u16 Ks[2][64 * 64];  // [s:64][d:64], swizzled
  __shared__ __align__(1024) u16 Vs[2][64 * 64];  // [d:64][s:64], swizzled
  __shared__ __align__(1024) u16 Ps[4][32 * 64];  // per-wave [q:32][s:64], swizzled
  const int bh = blockIdx.y, qt = blockIdx.x;
  const int tid = threadIdx.x, wave = tid >> 6, lane = tid & 63;
  const int lg = lane >> 4, ll = lane & 15;

  bfrag qf[2][2];
  const u16* Qb = Q + ((size_t)bh * TT + qt * 128 + wave * 32) * HS;
#pragma unroll
  for (int qb = 0; qb < 2; qb++)
#pragma unroll
    for (int dc = 0; dc < 2; dc++)
      qf[qb][dc] = *(const bfrag*)&Qb[(qb * 16 + ll) * HS + dc * 32 + lg * 8];

  f4 o[2][4] = {};
  float mrun[2] = {-INFINITY, -INFINITY}, lrun[2] = {0.f, 0.f};

  const int trow = tid >> 3;
  const int tch  = (tid & 7) ^ (trow & 7);
  const u16* gk = Kb + ((size_t)bh * TT + trow) * HS + tch * 8;
  const u16* gv = Vt + ((size_t)bh * HS + trow) * TT + tch * 8;

  char* const pw = (char*)Ps[wave];

#define STAGE(bufi, stt)                                                          \
  do {                                                                            \
    u16* lk = &Ks[bufi][tid * 8];                                                 \
    u16* lv = &Vs[bufi][tid * 8];                                                 \
    __builtin_amdgcn_global_load_lds(AS1(gk + (size_t)(stt) * HS), AS3(lk), 16, 0, 0); \
    __builtin_amdgcn_global_load_lds(AS1(gk + (size_t)(stt) * HS + 32 * HS), AS3(lk + 2048), 16, 0, 0); \
    __builtin_amdgcn_global_load_lds(AS1(gv + (stt)), AS3(lv), 16, 0, 0);         \
    __builtin_amdgcn_global_load_lds(AS1(gv + (stt) + (size_t)32 * TT), AS3(lv + 2048), 16, 0, 0); \
  } while (0)

  STAGE(0, 0);
  int cur = 0;

  for (int st = 0; st < TT; st += 64) {
    if (st + 64 < TT) {
      STAGE(cur ^ 1, st + 64);
      asm volatile("s_waitcnt vmcnt(4)" ::: "memory");
    } else {
      asm volatile("s_waitcnt vmcnt(0)" ::: "memory");
    }
    __builtin_amdgcn_s_barrier();
    __builtin_amdgcn_sched_barrier(0);

    const char* kbuf = (const char*)Ks[cur];
    const char* vbuf = (const char*)Vs[cur];

    f4 p[2][4];
#pragma unroll
    for (int kb = 0; kb < 4; kb++) {
      const int row = kb * 16 + ll;
      const bfrag k0 = *(const bfrag*)(kbuf + swz128(row * 128 + lg * 16));
      const bfrag k1 = *(const bfrag*)(kbuf + swz128(row * 128 + 64 + lg * 16));
#pragma unroll
      for (int qb = 0; qb < 2; qb++) {
        f4 z = {0.f, 0.f, 0.f, 0.f};
        z = __builtin_amdgcn_mfma_f32_16x16x32_bf16(k0, qf[qb][0], z, 0, 0, 0);
        p[qb][kb] = __builtin_amdgcn_mfma_f32_16x16x32_bf16(k1, qf[qb][1], z, 0, 0, 0);
      }
    }

#pragma unroll
    for (int qb = 0; qb < 2; qb++) {
      float pm = p[qb][0][0];
#pragma unroll
      for (int kb = 0; kb < 4; kb++)
#pragma unroll
        for (int r = 0; r < 4; r++)
          if (kb | r) pm = fmaxf(pm, p[qb][kb][r]);
      pm = fmaxf(pm, __shfl_xor(pm, 16));
      pm = fmaxf(pm, __shfl_xor(pm, 32));
      const float mn = fmaxf(mrun[qb], pm);
      const float al = __expf(mrun[qb] - mn);
      mrun[qb] = mn;
      float rs = 0.f;
#pragma unroll
      for (int kb = 0; kb < 4; kb++)
#pragma unroll
        for (int r = 0; r < 4; r++) {
          const float e = __expf(p[qb][kb][r] - mn);
          p[qb][kb][r] = e;
          rs += e;
        }
      rs += __shfl_xor(rs, 16);
      rs += __shfl_xor(rs, 32);
      lrun[qb] = lrun[qb] * al + rs;
#pragma unroll
      for (int fo = 0; fo < 4; fo++) o[qb][fo] *= al;
#pragma unroll
      for (int kb = 0; kb < 4; kb++) {
        union { uint2 v; __bf16 h[4]; } w;
        w.h[0] = (__bf16)p[qb][kb][0];
        w.h[1] = (__bf16)p[qb][kb][1];
        w.h[2] = (__bf16)p[qb][kb][2];
        w.h[3] = (__bf16)p[qb][kb][3];
        *(uint2*)(pw + swz128((qb * 16 + ll) * 128 + kb * 32 + lg * 8)) = w.v;
      }
    }

#pragma unroll
    for (int ks = 0; ks < 2; ks++) {
      const bfrag pb0 = *(const bfrag*)(pw + swz128(ll * 128 + ks * 64 + lg * 16));
      const bfrag pb1 = *(const bfrag*)(pw + swz128((16 + ll) * 128 + ks * 64 + lg * 16));
#pragma unroll
      for (int fo = 0; fo < 4; fo++) {
        const bfrag vf = *(const bfrag*)(vbuf + swz128((fo * 16 + ll) * 128 + ks * 64 + lg * 16));
        o[0][fo] = __builtin_amdgcn_mfma_f32_16x16x32_bf16(vf, pb0, o[0][fo], 0, 0, 0);
        o[1][fo] = __builtin_amdgcn_mfma_f32_16x16x32_bf16(vf, pb1, o[1][fo], 0, 0, 0);
      }
    }

    __builtin_amdgcn_sched_barrier(0);
    __builtin_amdgcn_s_barrier();
    cur ^= 1;
  }
#undef STAGE

  const int b = bh >> 4, h = bh & 15;
#pragma unroll
  for (int qb = 0; qb < 2; qb++) {
    const float inv = 1.0f / lrun[qb];
    const int t = qt * 128 + wave * 32 + qb * 16 + ll;
#pragma unroll
    for (int fo = 0; fo < 4; fo++) {
      union { uint2 v; __bf16 h[4]; } w;
      w.h[0] = (__bf16)(o[qb][fo][0] * inv);
      w.h[1] = (__bf16)(o[qb][fo][1] * inv);
      w.h[2] = (__bf16)(o[qb][fo][2] * inv);
      w.h[3] = (__bf16)(o[qb][fo][3] * inv);
      *(uint2*)&Ao[((size_t)b * TT + t) * CC + h * HS + fo * 16 + lg * 4] = w.v;
    }
  }
}

// ------------------------------------------------------------------
extern "C" void kernel_launch(void* const* d_in, const int* in_sizes, int n_in,
                              void* d_out, int out_size, void* d_ws, size_t ws_size,
                              hipStream_t stream) {
  const float* x    = (const float*)d_in[0];
  const float* Wq   = (const float*)d_in[1];
  const float* bq   = (const float*)d_in[2];
  const float* Wk   = (const float*)d_in[3];
  const float* bk   = (const float*)d_in[4];
  const float* Wv   = (const float*)d_in[5];
  const float* bv   = (const float*)d_in[6];
  const float* Wp   = (const float*)d_in[7];
  const float* bp   = (const float*)d_in[8];
  const float* W1   = (const float*)d_in[9];
  const float* b1   = (const float*)d_in[10];
  const float* W2   = (const float*)d_in[11];
  const float* b2   = (const float*)d_in[12];
  const float* ln1w = (const float*)d_in[13];
  const float* ln1b = (const float*)d_in[14];
  const float* ln2w = (const float*)d_in[15];
  const float* ln2b = (const float*)d_in[16];
  float* dout = (float*)d_out;

  char* ws = (char*)d_ws;
  u16* wqkv = (u16*)(ws + 0);          // [3072][1024]  6.29 MB
  u16* wpt  = (u16*)(ws + 6291456);    // [1024][1024]  2.10 MB
  u16* w1t  = (u16*)(ws + 8388608);    // [4096][1024]  8.39 MB
  u16* w2t  = (u16*)(ws + 16777216);   // [1024][4096]  8.39 MB
  u16* xn   = (u16*)(ws + 25165824);   // [4096][1024]  8.39 MB (reused as LN2 out)
  u16* qb   = (u16*)(ws + 33554432);   // [32][2048][64]
  u16* kb   = (u16*)(ws + 41943040);
  u16* vb   = (u16*)(ws + 50331648);
  u16* vt   = (u16*)(ws + 58720256);   // [32][64][2048]
  u16* ao   = (u16*)(ws + 67108864);   // [4096][1024]
  u16* hb   = qb;                      // FFN hidden overlays q/k/v/vt (33.55 MB)

  dim3 blk256(256);
  dim3 blkT(32, 8);

  // weight prep: transpose to [N][K] bf16
  tr_f32_bf16<<<dim3(2, 32, 16), blkT, 0, stream>>>(Wq, wqkv,               1024,   64, 65536LL, 65536LL, 1024);
  tr_f32_bf16<<<dim3(2, 32, 16), blkT, 0, stream>>>(Wk, wqkv + 1024 * 1024, 1024,   64, 65536LL, 65536LL, 1024);
  tr_f32_bf16<<<dim3(2, 32, 16), blkT, 0, stream>>>(Wv, wqkv + 2048 * 1024, 1024,   64, 65536LL, 65536LL, 1024);
  tr_f32_bf16<<<dim3(32, 32, 1),  blkT, 0, stream>>>(Wp, wpt, 1024, 1024, 0LL, 0LL, 1024);
  tr_f32_bf16<<<dim3(128, 32, 1), blkT, 0, stream>>>(W1, w1t, 1024, 4096, 0LL, 0LL, 1024);
  tr_f32_bf16<<<dim3(32, 128, 1), blkT, 0, stream>>>(W2, w2t, 4096, 1024, 0LL, 0LL, 4096);

  // LN1 -> xn (bf16)
  ln_kernel<<<dim3(MT), blk256, 0, stream>>>(x, ln1w, ln1b, xn);

  // QKV projection (q pre-scaled by C^-0.5)
  gemm_qkv<<<dim3(24, 32), blk256, 0, stream>>>(xn, wqkv, bq, bk, bv, qb, kb, vb);

  // V -> Vt [bh][64][2048]
  tr_bf16<<<dim3(2, 64, 32), blkT, 0, stream>>>(vb, vt, 2048, 64, 131072LL, 131072LL, 2048);

  // attention
  attn_kernel<<<dim3(16, 32), blk256, 0, stream>>>(qb, kb, vt, ao);

  // out = x + ao @ Wp + bp   (f32, into d_out)   BN=64 -> 512 blocks
  gemm_proj<<<dim3(16, 32), blk256, 0, stream>>>(ao, wpt, bp, x, dout);

  // LN2 -> xn (reuse)
  ln_kernel<<<dim3(MT), blk256, 0, stream>>>(dout, ln2w, ln2b, xn);

  // FFN
  gemm_ffn1<<<dim3(32, 32), blk256, 0, stream>>>(xn, w1t, b1, hb);
  gemm_ffn2<<<dim3(16, 32), blk256, 0, stream>>>(hb, w2t, b2, dout, dout);
}